// Round 5
// baseline (25.787 us; speedup 1.0000x reference)
//
#include <hip/hip_runtime.h>
#include <math.h>

// Cox partial log-likelihood, N=8192 — single-dispatch, fence-free.
// loss = -mean_i ( (hazard[i] - log( sum_j exp(hazard[j]) * [time[j]>=time[i]] )) * censor[i] )
//
// R5: R3-vs-R4 showed (a) inter-node gap ~4us dominates a 2-dispatch graph,
// (b) __threadfence = per-XCD L2 writeback = death, but plain global atomics
// are device-coherent with no fence. So: ONE kernel, no j-split (each block
// stages all 8192 (t,e) in 64KB LDS and fully computes its 16 risk sums),
// cross-block combine via atomics ONLY:
//   atomicAdd(acc, part); s_waitcnt vmcnt(0); c = atomicAdd(cnt,1);
//   c==511 -> all 512 acc-adds complete at the coherent point -> read acc,
//   write out, reset acc/cnt for next replay. Poison (0xAA) cleared by CAS.
// 512 blocks x 16 i (4 waves, IPT=4), __launch_bounds__(256,2): 2 blocks/CU,
// VALU (6144 cyc/CU) ~= LDS b128 reads (6144 cyc/CU), overlapped.

#define COX_N   8192
#define TPB     256
#define NBLK    512
#define IPT     4
#define I_PER_BLOCK 16                      // 4 waves * IPT; 512*16 = 8192
#define POISON  0xAAAAAAAAu

__device__ __forceinline__ float merge_pair(float a, float b, int takeB, int off) {
    // Pair-reduce a and b over lanes differing in `off`; keep b-side if takeB.
    float am = a + __shfl_xor(a, off, 64);
    float bm = b + __shfl_xor(b, off, 64);
    return takeB ? bm : am;
}

__global__ __launch_bounds__(TPB, 2) void cox_one(const float* __restrict__ hazard,
                                                  const float* __restrict__ time_,
                                                  const float* __restrict__ censor,
                                                  float* __restrict__ out,
                                                  float* __restrict__ acc,
                                                  unsigned int* __restrict__ cnt) {
    __shared__ __align__(16) float t_lds[COX_N];
    __shared__ __align__(16) float e_lds[COX_N];
    __shared__ float red[4 * IPT];

    const int t    = threadIdx.x;
    const int lane = t & 63;
    const int wid  = t >> 6;
    const int iBase = blockIdx.x * I_PER_BLOCK + wid * IPT;

    // i-side times (wave-uniform -> scalar loads).
    const float ti0 = time_[iBase + 0];
    const float ti1 = time_[iBase + 1];
    const float ti2 = time_[iBase + 2];
    const float ti3 = time_[iBase + 3];

    // Stage all 8192 (t, exp(h)) into LDS: 8 float4 per thread per array.
    {
        const float4* tg = reinterpret_cast<const float4*>(time_);
        const float4* hg = reinterpret_cast<const float4*>(hazard);
        float4* tl = reinterpret_cast<float4*>(t_lds);
        float4* el = reinterpret_cast<float4*>(e_lds);
        #pragma unroll
        for (int r = 0; r < COX_N / 4 / TPB; ++r) {      // 8 iterations
            const int idx = r * TPB + t;
            const float4 tv = tg[idx];
            const float4 hv = hg[idx];
            float4 ev;
            ev.x = __expf(hv.x); ev.y = __expf(hv.y);
            ev.z = __expf(hv.z); ev.w = __expf(hv.w);
            tl[idx] = tv;
            el[idx] = ev;
        }
    }
    __syncthreads();

    float acc0 = 0.0f, acc1 = 0.0f, acc2 = 0.0f, acc3 = 0.0f;

    // Full j-sweep: lane l reads j = k*256 + 4l (+0..3); contiguous 1KB/wave
    // ds_read_b128, conflict-free (2-way aliasing is free). 32 k-iterations.
    #pragma unroll 4
    for (int k = 0; k < COX_N / 256; ++k) {
        const int j = (k << 8) + (lane << 2);
        const float4 tj = *reinterpret_cast<const float4*>(t_lds + j);
        const float4 ej = *reinterpret_cast<const float4*>(e_lds + j);
        acc0 += (tj.x >= ti0) ? ej.x : 0.0f;
        acc1 += (tj.x >= ti1) ? ej.x : 0.0f;
        acc2 += (tj.x >= ti2) ? ej.x : 0.0f;
        acc3 += (tj.x >= ti3) ? ej.x : 0.0f;
        acc0 += (tj.y >= ti0) ? ej.y : 0.0f;
        acc1 += (tj.y >= ti1) ? ej.y : 0.0f;
        acc2 += (tj.y >= ti2) ? ej.y : 0.0f;
        acc3 += (tj.y >= ti3) ? ej.y : 0.0f;
        acc0 += (tj.z >= ti0) ? ej.z : 0.0f;
        acc1 += (tj.z >= ti1) ? ej.z : 0.0f;
        acc2 += (tj.z >= ti2) ? ej.z : 0.0f;
        acc3 += (tj.z >= ti3) ? ej.z : 0.0f;
        acc0 += (tj.w >= ti0) ? ej.w : 0.0f;
        acc1 += (tj.w >= ti1) ? ej.w : 0.0f;
        acc2 += (tj.w >= ti2) ? ej.w : 0.0f;
        acc3 += (tj.w >= ti3) ? ej.w : 0.0f;
    }

    // Merged butterfly: 10 shuffles; lane l ends with full rs of acc[l & 3].
    const int b0 = lane & 1, b1 = lane & 2;
    float w0 = merge_pair(acc0, acc1, b0, 1);
    float w1 = merge_pair(acc2, acc3, b0, 1);
    float y  = merge_pair(w0, w1, b1, 2);
    y += __shfl_xor(y, 4, 64);
    y += __shfl_xor(y, 8, 64);
    y += __shfl_xor(y, 16, 64);
    y += __shfl_xor(y, 32, 64);

    // Per-i loss terms (lanes 0..3 of each wave).
    if (lane < IPT) {
        const int i = iBase + lane;
        red[wid * IPT + lane] = (hazard[i] - logf(y)) * censor[i];
    }
    __syncthreads();

    // Fence-free atomic epilogue (thread 0 only).
    if (t == 0) {
        float part = 0.0f;
        #pragma unroll
        for (int k = 0; k < 4 * IPT; ++k) part += red[k];

        // First-touch poison clear (harness poisons ws to 0xAA once).
        atomicCAS(cnt, POISON, 0u);
        atomicCAS(reinterpret_cast<unsigned int*>(acc), POISON, 0u);

        const float old = atomicAdd(acc, part);
        asm volatile("" ::"v"(old));                    // keep ack live
        asm volatile("s_waitcnt vmcnt(0)" ::: "memory"); // acc-add ACKed before cnt-add
        const unsigned int c = atomicAdd(cnt, 1u);
        if (c == NBLK - 1) {
            // All 512 acc-adds complete at the coherent point (each block
            // waited for its acc ack before its cnt add). Atomic read:
            const float total = atomicAdd(acc, 0.0f);
            out[0] = -total / (float)COX_N;
            atomicExch(acc, 0.0f);                      // reset for next replay
            atomicExch(cnt, 0u);
        }
    }
}

extern "C" void kernel_launch(void* const* d_in, const int* in_sizes, int n_in,
                              void* d_out, int out_size, void* d_ws, size_t ws_size,
                              hipStream_t stream) {
    const float* hazard = (const float*)d_in[0];
    const float* time_  = (const float*)d_in[1];
    const float* censor = (const float*)d_in[2];
    float* out = (float*)d_out;
    float* acc = (float*)d_ws;                          // ws[0]
    unsigned int* cnt = (unsigned int*)d_ws + 16;       // 64B away, same line never shared

    hipLaunchKernelGGL(cox_one, dim3(NBLK), dim3(TPB), 0, stream,
                       hazard, time_, censor, out, acc, cnt);
}

// Round 6
// 15.667 us; speedup vs baseline: 1.6459x; 1.6459x over previous
//
#include <hip/hip_runtime.h>
#include <math.h>

// Cox partial log-likelihood, N=8192 — single-dispatch, fence-free, low-contention tail.
// loss = -mean_i ( (hazard[i] - log( sum_j exp(hazard[j]) * [time[j]>=time[i]] )) * censor[i] )
//
// R6: R5's compute kept (exact, conflict-free); tail rebuilt. R5 funneled
// ~2000 same-line atomics through one coherent point (~10ns each = 19us).
// Now: 512 blocks -> 64 groups of 8. Per block: accf[g] += part (8/line,
// 64 lines); vmcnt(0); cntg[g]++ (8/line). Group-last bumps cnt2 (64 on one
// line). Winner: 64 lanes read accf[0..63] in one parallel round trip,
// butterfly-reduce, write out, reset counters for next graph replay.
// Atomic-return-value dependency chains give cross-block ordering with NO
// __threadfence (R3's fence version: 53us).

#define COX_N   8192
#define TPB     256
#define NBLK    512
#define IPT     4
#define I_PER_BLOCK 16                      // 4 waves * IPT; 512*16 = 8192
#define POISON  0xAAAAAAAAu
#define NGRP    64                          // 512 / 8 blocks per group
// ws layout (units: u32/float, stride 16 = one 64B line per slot):
//   accf[g]  at ws[g*16],        g in [0,64)
//   cntg[g]  at ws[1024 + g*16], g in [0,64)
//   cnt2     at ws[2048]

__device__ __forceinline__ float merge_pair(float a, float b, int takeB, int off) {
    float am = a + __shfl_xor(a, off, 64);
    float bm = b + __shfl_xor(b, off, 64);
    return takeB ? bm : am;
}

__global__ __launch_bounds__(TPB, 2) void cox_one(const float* __restrict__ hazard,
                                                  const float* __restrict__ time_,
                                                  const float* __restrict__ censor,
                                                  float* __restrict__ out,
                                                  float* __restrict__ ws_f,
                                                  unsigned int* __restrict__ ws_u) {
    __shared__ __align__(16) float t_lds[COX_N];
    __shared__ __align__(16) float e_lds[COX_N];
    __shared__ float red[4 * IPT];
    __shared__ int s_win;

    const int t    = threadIdx.x;
    const int lane = t & 63;
    const int wid  = t >> 6;
    const int iBase = blockIdx.x * I_PER_BLOCK + wid * IPT;

    // i-side times (wave-uniform).
    const float ti0 = time_[iBase + 0];
    const float ti1 = time_[iBase + 1];
    const float ti2 = time_[iBase + 2];
    const float ti3 = time_[iBase + 3];

    // Stage all 8192 (t, exp(h)) into LDS: 8 float4 per thread per array.
    {
        const float4* tg = reinterpret_cast<const float4*>(time_);
        const float4* hg = reinterpret_cast<const float4*>(hazard);
        float4* tl = reinterpret_cast<float4*>(t_lds);
        float4* el = reinterpret_cast<float4*>(e_lds);
        #pragma unroll
        for (int r = 0; r < COX_N / 4 / TPB; ++r) {      // 8 iterations
            const int idx = r * TPB + t;
            const float4 tv = tg[idx];
            const float4 hv = hg[idx];
            float4 ev;
            ev.x = __expf(hv.x); ev.y = __expf(hv.y);
            ev.z = __expf(hv.z); ev.w = __expf(hv.w);
            tl[idx] = tv;
            el[idx] = ev;
        }
    }
    __syncthreads();

    float acc0 = 0.0f, acc1 = 0.0f, acc2 = 0.0f, acc3 = 0.0f;

    // Full j-sweep: lane l reads j = k*256 + 4l (+0..3); contiguous 1KB/wave
    // ds_read_b128, conflict-free. 32 k-iterations.
    #pragma unroll 4
    for (int k = 0; k < COX_N / 256; ++k) {
        const int j = (k << 8) + (lane << 2);
        const float4 tj = *reinterpret_cast<const float4*>(t_lds + j);
        const float4 ej = *reinterpret_cast<const float4*>(e_lds + j);
        acc0 += (tj.x >= ti0) ? ej.x : 0.0f;
        acc1 += (tj.x >= ti1) ? ej.x : 0.0f;
        acc2 += (tj.x >= ti2) ? ej.x : 0.0f;
        acc3 += (tj.x >= ti3) ? ej.x : 0.0f;
        acc0 += (tj.y >= ti0) ? ej.y : 0.0f;
        acc1 += (tj.y >= ti1) ? ej.y : 0.0f;
        acc2 += (tj.y >= ti2) ? ej.y : 0.0f;
        acc3 += (tj.y >= ti3) ? ej.y : 0.0f;
        acc0 += (tj.z >= ti0) ? ej.z : 0.0f;
        acc1 += (tj.z >= ti1) ? ej.z : 0.0f;
        acc2 += (tj.z >= ti2) ? ej.z : 0.0f;
        acc3 += (tj.z >= ti3) ? ej.z : 0.0f;
        acc0 += (tj.w >= ti0) ? ej.w : 0.0f;
        acc1 += (tj.w >= ti1) ? ej.w : 0.0f;
        acc2 += (tj.w >= ti2) ? ej.w : 0.0f;
        acc3 += (tj.w >= ti3) ? ej.w : 0.0f;
    }

    // Merged butterfly: 10 shuffles; lane l ends with full rs of acc[l & 3].
    const int b0 = lane & 1, b1 = lane & 2;
    float w0 = merge_pair(acc0, acc1, b0, 1);
    float w1 = merge_pair(acc2, acc3, b0, 1);
    float y  = merge_pair(w0, w1, b1, 2);
    y += __shfl_xor(y, 4, 64);
    y += __shfl_xor(y, 8, 64);
    y += __shfl_xor(y, 16, 64);
    y += __shfl_xor(y, 32, 64);

    if (lane < IPT) {
        const int i = iBase + lane;
        red[wid * IPT + lane] = (hazard[i] - logf(y)) * censor[i];
    }
    __syncthreads();

    // ---- low-contention fence-free tail ----
    if (t == 0) {
        float part = 0.0f;
        #pragma unroll
        for (int k = 0; k < 4 * IPT; ++k) part += red[k];

        const unsigned int g = blockIdx.x >> 3;            // group 0..63
        unsigned int* accu = ws_u + g * 16;
        unsigned int* cg   = ws_u + 1024 + g * 16;
        unsigned int* c2   = ws_u + 2048;

        // First-touch poison clear (8 CAS/line max, spread over 64 lines).
        atomicCAS(accu, POISON, 0u);
        atomicCAS(cg,   POISON, 0u);

        const float old = atomicAdd(reinterpret_cast<float*>(accu), part);
        asm volatile("" ::"v"(old));
        asm volatile("s_waitcnt vmcnt(0)" ::: "memory");   // accf-add ACKed
        const unsigned int c = atomicAdd(cg, 1u);
        int w = 0;
        if (c == 8 - 1) {                                  // last in group
            atomicCAS(c2, POISON, 0u);
            asm volatile("s_waitcnt vmcnt(0)" ::: "memory");
            const unsigned int cc = atomicAdd(c2, 1u);
            w = (cc == NGRP - 1);
        }
        s_win = w;
    }
    __syncthreads();

    // ---- winner: combine 64 group sums, write out, reset for next replay ----
    if (s_win && wid == 0) {
        float v = atomicAdd(ws_f + lane * 16, 0.0f);       // parallel read of accf[lane]
        #pragma unroll
        for (int off = 32; off > 0; off >>= 1) v += __shfl_xor(v, off, 64);
        if (lane == 0) out[0] = -v / (float)COX_N;
        // v consumed -> reads complete; now safe to reset.
        atomicExch(ws_u + lane * 16, 0u);                  // accf[lane] = 0.0f
        atomicExch(ws_u + 1024 + lane * 16, 0u);           // cntg[lane] = 0
        if (lane == 0) atomicExch(ws_u + 2048, 0u);        // cnt2 = 0
    }
}

extern "C" void kernel_launch(void* const* d_in, const int* in_sizes, int n_in,
                              void* d_out, int out_size, void* d_ws, size_t ws_size,
                              hipStream_t stream) {
    const float* hazard = (const float*)d_in[0];
    const float* time_  = (const float*)d_in[1];
    const float* censor = (const float*)d_in[2];
    float* out = (float*)d_out;
    float* ws_f = (float*)d_ws;
    unsigned int* ws_u = (unsigned int*)d_ws;

    hipLaunchKernelGGL(cox_one, dim3(NBLK), dim3(TPB), 0, stream,
                       hazard, time_, censor, out, ws_f, ws_u);
}

// Round 7
// 15.468 us; speedup vs baseline: 1.6671x; 1.0129x over previous
//
#include <hip/hip_runtime.h>
#include <math.h>

// Cox partial log-likelihood, N=8192 — binned suffix-sum algorithm, single dispatch.
// loss = -mean_i ( (hazard[i] - log( sum_j exp(hazard[j]) * [time[j]>=time[i]] )) * censor[i] )
//
// R7: stop brute-forcing O(N^2) (R2/R4/R6 show ~8-13us however tuned).
// risk_sum is a 1-D suffix sum over time order. EXACT binned decomposition:
// time ~ U[0,1); bin b(t) = clamp(floor(t*NB)). For i in bin b_i:
//   rs_i = (total - incl_binsum[b_i]) + sum_{j in bin b_i} e_j * [t_j >= t_i]
// Cross-bin terms are exact (higher bin => t_j > t_i strictly; lower => t_j < t_i);
// ties land in the same bin and are compared explicitly. Work: 64M pairs ->
// ~73K pairs + O(N) binning (~800x less).
// 32 blocks x 256 threads; each block independently: histogram -> scan ->
// scatter (counting sort by bin, LDS) -> bin sums -> inclusive scan -> its
// 256 i's. Combine 32 block losses via R6's proven fence-free atomic tail.

#define COX_N   8192
#define TPB     256
#define NBLK    32
#define NB      1024
#define BPT     (NB / TPB)                 // 4 bins per thread
#define POISON  0xAAAAAAAAu

__device__ __forceinline__ int bin_of(float t) {
    int b = (int)(t * (float)NB);          // t in [0,1) -> 0..NB-1
    b = b < 0 ? 0 : b;
    return b > NB - 1 ? NB - 1 : b;
}

__global__ __launch_bounds__(TPB) void cox_binned(const float* __restrict__ hazard,
                                                  const float* __restrict__ time_,
                                                  const float* __restrict__ censor,
                                                  float* __restrict__ out,
                                                  float* __restrict__ ws_f,
                                                  unsigned int* __restrict__ ws_u) {
    __shared__ __align__(16) float st[COX_N];          // sorted-by-bin times
    __shared__ __align__(16) float se[COX_N];          // sorted-by-bin exp(hazard)
    __shared__ unsigned int bincnt[NB];
    __shared__ unsigned int binstart[NB];
    __shared__ unsigned int bincur[NB];
    __shared__ float binincl[NB];                      // inclusive prefix of bin sums
    __shared__ unsigned int utot[4];
    __shared__ float ftot[4];
    __shared__ float red[4];
    __shared__ float s_total;
    __shared__ int s_win;

    const int t    = threadIdx.x;
    const int lane = t & 63;
    const int wid  = t >> 6;

    // ---- 1. zero histogram ----
    #pragma unroll
    for (int k = 0; k < BPT; ++k) bincnt[t + k * TPB] = 0u;
    __syncthreads();

    // ---- 2. histogram over time (float4 pass) ----
    const float4* tg = reinterpret_cast<const float4*>(time_);
    const float4* hg = reinterpret_cast<const float4*>(hazard);
    #pragma unroll
    for (int r = 0; r < COX_N / 4 / TPB; ++r) {        // 8 iterations
        const float4 tv = tg[r * TPB + t];
        atomicAdd(&bincnt[bin_of(tv.x)], 1u);
        atomicAdd(&bincnt[bin_of(tv.y)], 1u);
        atomicAdd(&bincnt[bin_of(tv.z)], 1u);
        atomicAdd(&bincnt[bin_of(tv.w)], 1u);
    }
    __syncthreads();

    // ---- 3. exclusive scan of counts -> binstart, bincur ----
    {
        unsigned int c[BPT];
        #pragma unroll
        for (int k = 0; k < BPT; ++k) c[k] = bincnt[t * BPT + k];
        unsigned int L = 0;
        #pragma unroll
        for (int k = 0; k < BPT; ++k) L += c[k];
        unsigned int incl = L;
        #pragma unroll
        for (int off = 1; off < 64; off <<= 1) {
            unsigned int u = __shfl_up(incl, off, 64);
            if (lane >= off) incl += u;
        }
        if (lane == 63) utot[wid] = incl;
        __syncthreads();
        unsigned int woff = 0;
        #pragma unroll
        for (int w = 0; w < 4; ++w) woff += (w < wid) ? utot[w] : 0u;
        unsigned int s = woff + incl - L;              // exclusive start of this thread's group
        #pragma unroll
        for (int k = 0; k < BPT; ++k) {
            binstart[t * BPT + k] = s;
            bincur[t * BPT + k]   = s;
            s += c[k];
        }
    }
    __syncthreads();

    // ---- 4. scatter (counting sort by bin) + exp ----
    #pragma unroll
    for (int r = 0; r < COX_N / 4 / TPB; ++r) {
        const int idx = r * TPB + t;
        const float4 tv = tg[idx];
        const float4 hv = hg[idx];
        unsigned int p;
        p = atomicAdd(&bincur[bin_of(tv.x)], 1u); st[p] = tv.x; se[p] = __expf(hv.x);
        p = atomicAdd(&bincur[bin_of(tv.y)], 1u); st[p] = tv.y; se[p] = __expf(hv.y);
        p = atomicAdd(&bincur[bin_of(tv.z)], 1u); st[p] = tv.z; se[p] = __expf(hv.z);
        p = atomicAdd(&bincur[bin_of(tv.w)], 1u); st[p] = tv.w; se[p] = __expf(hv.w);
    }
    __syncthreads();

    // ---- 5. per-bin sums + inclusive scan -> binincl, total ----
    {
        float s[BPT];
        #pragma unroll
        for (int k = 0; k < BPT; ++k) {
            const int b = t * BPT + k;
            const unsigned int s0 = binstart[b], n = bincnt[b];
            float acc = 0.0f;
            for (unsigned int p = 0; p < n; ++p) acc += se[s0 + p];
            s[k] = acc;
        }
        float L = 0.0f;
        #pragma unroll
        for (int k = 0; k < BPT; ++k) L += s[k];
        float incl = L;
        #pragma unroll
        for (int off = 1; off < 64; off <<= 1) {
            float u = __shfl_up(incl, off, 64);
            if (lane >= off) incl += u;
        }
        if (lane == 63) ftot[wid] = incl;
        __syncthreads();
        float woff = 0.0f;
        #pragma unroll
        for (int w = 0; w < 4; ++w) woff += (w < wid) ? ftot[w] : 0.0f;
        float ex = woff + incl - L;                    // exclusive prefix for this group
        #pragma unroll
        for (int k = 0; k < BPT; ++k) {
            ex += s[k];
            binincl[t * BPT + k] = ex;                 // inclusive through bin
        }
        if (t == TPB - 1) s_total = ex;
    }
    __syncthreads();

    // ---- 6. this block's 256 i's ----
    const int i  = blockIdx.x * TPB + t;
    const float ti = time_[i];
    const float hi = hazard[i];
    const float ci = censor[i];
    const int bi = bin_of(ti);
    float rs = s_total - binincl[bi];                  // all bins strictly above
    {
        const unsigned int s0 = binstart[bi], n = bincnt[bi];
        for (unsigned int p = 0; p < n; ++p)
            rs += (st[s0 + p] >= ti) ? se[s0 + p] : 0.0f;
    }
    float li = (hi - logf(rs)) * ci;

    // ---- 7. block reduce ----
    #pragma unroll
    for (int off = 32; off > 0; off >>= 1) li += __shfl_xor(li, off, 64);
    if (lane == 0) red[wid] = li;
    __syncthreads();

    // ---- 8. fence-free atomic tail (32 blocks, trivial contention) ----
    if (t == 0) {
        const float part = red[0] + red[1] + red[2] + red[3];
        unsigned int* accu = ws_u;                     // line 0
        unsigned int* cnt  = ws_u + 16;                // line 1
        atomicCAS(accu, POISON, 0u);
        atomicCAS(cnt,  POISON, 0u);
        const float old = atomicAdd(reinterpret_cast<float*>(accu), part);
        asm volatile("" ::"v"(old));
        asm volatile("s_waitcnt vmcnt(0)" ::: "memory");   // acc-add ACKed before cnt-add
        const unsigned int c = atomicAdd(cnt, 1u);
        s_win = (c == NBLK - 1);
    }
    __syncthreads();
    if (s_win && t == 0) {
        const float total = atomicAdd(ws_f, 0.0f);     // all 32 adds complete
        out[0] = -total / (float)COX_N;
        atomicExch(ws_u, 0u);                          // reset for next replay
        atomicExch(ws_u + 16, 0u);
    }
}

extern "C" void kernel_launch(void* const* d_in, const int* in_sizes, int n_in,
                              void* d_out, int out_size, void* d_ws, size_t ws_size,
                              hipStream_t stream) {
    const float* hazard = (const float*)d_in[0];
    const float* time_  = (const float*)d_in[1];
    const float* censor = (const float*)d_in[2];
    float* out = (float*)d_out;
    float* ws_f = (float*)d_ws;
    unsigned int* ws_u = (unsigned int*)d_ws;

    hipLaunchKernelGGL(cox_binned, dim3(NBLK), dim3(TPB), 0, stream,
                       hazard, time_, censor, out, ws_f, ws_u);
}